// Round 16
// baseline (366.059 us; speedup 1.0000x reference)
//
#include <hip/hip_runtime.h>
#include <math.h>

#define NN 10000
#define NE 100000
#define CC 6
#define LL 6
#define BB 16
#define FUNC_LO 100
#define FUNC_HI 9900
#define NOUT 100
#define EPSF 1e-5f
#define NSLOT 64

struct Slot { double s1, s2; double pad[6]; };  // 64B-padded

struct Params {
  const float *x, *w1v, *b1, *w2v, *b2, *w3v, *b3, *gamma, *beta;
  const int *src, *dst, *w3r, *w3c;
  float *out;
  int *row_start, *counts, *fill, *slot;     // dst-CSR rows; slot[e] = position of e
  int *row2, *counts2, *fill2, *csr2;        // func node -> outgoing selected-edge rows (k)
  uint4 *grec;    // per dst-slot: {bf16 w1[0,1] | w1[2,3] | w1[4,5] | src}
  uint4 *srec;    // per src-slot: {bf16 w3[0,1] | w3[2,3] | w3[4,5] | slot}
  unsigned short *sb3;         // per src-slot: bf16(b3)
  float *xT, *h;
  unsigned short *z3a, *z3b;   // bf16 z3, [slot][16]
  unsigned short *A;           // bf16 [F][CC][BB] running A = sum h*w1
  float *Cw;                   // f32  [F][CC]    constant C = sum w1 (bf16-rounded w1)
  Slot *part, *baseS;
  float2 *mv;                  // per layer {mean, inv}
  int *done;                   // done counters: [0..LL-1]=AB, [LL]=P1
  int F, Ksel;
};

__device__ __forceinline__ float eluf(float x){ return x > 0.0f ? x : expm1f(x); }
__device__ __forceinline__ float bf2f(unsigned short h){
  union { unsigned int u; float f; } c; c.u = ((unsigned int)h)<<16; return c.f;
}
__device__ __forceinline__ unsigned short f2bf(float f){
  union { float f; unsigned int u; } c; c.f = f;
  return (unsigned short)((c.u + 0x7FFFu + ((c.u>>16)&1u)) >> 16);
}
__device__ __forceinline__ unsigned int packbf(float a, float b){
  return (unsigned int)f2bf(a) | ((unsigned int)f2bf(b)<<16);
}
__device__ __forceinline__ float2 ubf2(unsigned int u){
  union { unsigned int u; float f; } lo, hi;
  lo.u = u<<16; hi.u = u & 0xFFFF0000u;
  return make_float2(lo.f, hi.f);
}

__device__ void block_add_slot(double a, double q, Slot* sl){
  __shared__ double sb1[4], sb2[4];
  #pragma unroll
  for(int off=32;off;off>>=1){ a+=__shfl_down(a,off); q+=__shfl_down(q,off); }
  int wid = threadIdx.x>>6;
  if((threadIdx.x&63)==0){ sb1[wid]=a; sb2[wid]=q; }
  __syncthreads();
  if(threadIdx.x==0){
    double A=sb1[0]+sb1[1]+sb1[2]+sb1[3];
    double Q=sb2[0]+sb2[1]+sb2[2]+sb2[3];
    if(A!=0.0) atomicAdd(&sl->s1,A);
    if(Q!=0.0) atomicAdd(&sl->s2,Q);
  }
  __syncthreads();
}

// Last-finishing block of layer l reduces part[l]+baseS -> mv[l] = {m, inv}.
// part slots were written with device-scope atomics; read them back with
// atomic loads (atomicAdd 0.0) for cross-XCD coherence.
__device__ void finalize_bn(const Params& p, int l){
  __shared__ int sFin;
  if(threadIdx.x==0){
    __threadfence();
    int old=atomicAdd(&p.done[l],1);
    sFin = (old==(int)gridDim.x-1);
  }
  __syncthreads();
  if(sFin && threadIdx.x<64){
    Slot* pl=&p.part[l*NSLOT+threadIdx.x];
    double s1=atomicAdd(&pl->s1,0.0)+p.baseS[threadIdx.x].s1;
    double s2=atomicAdd(&pl->s2,0.0)+p.baseS[threadIdx.x].s2;
    #pragma unroll
    for(int off=32;off;off>>=1){ s1+=__shfl_down(s1,off); s2+=__shfl_down(s2,off); }
    if(threadIdx.x==0){
      const double cnt=(double)NE*(double)BB;
      double md=s1/cnt, vd=s2/cnt-md*md;
      p.mv[l]=make_float2((float)md,(float)(1.0/sqrt(vd+(double)EPSF)));
    }
  }
}

// Single-block scan with atomic loads (counters were device-scope atomics).
__device__ void scan_one(int* cin, int* rout, int nel){
  __shared__ int s_scan[256];
  const int CH=(nel+255)/256;
  int t=threadIdx.x, base=t*CH, s=0;
  for(int k=0;k<CH;k++){ int i=base+k; if(i<nel) s+=atomicAdd(&cin[i],0); }
  s_scan[t]=s; __syncthreads();
  for(int off=1;off<256;off<<=1){
    int v=(t>=off)?s_scan[t-off]:0; __syncthreads();
    s_scan[t]+=v; __syncthreads();
  }
  int run=s_scan[t]-s;
  for(int k=0;k<CH;k++){
    int i=base+k;
    if(i<nel){ rout[i]=run; run+=atomicAdd(&cin[i],0); }
  }
  if(t==255) rout[nel]=s_scan[255];
}

// P1: transpose x -> xT; dst histogram; src-selected histogram; base BN sums;
// zero out; LAST BLOCK scans both histograms into CSR row arrays.
__global__ __launch_bounds__(256) void kw_P1(Params p){
  int tid = blockIdx.x*256 + threadIdx.x, nt = gridDim.x*256;
  for(int i=tid;i<NN*BB;i+=nt){ int n=i>>4, b=i&15; p.xT[i]=p.x[b*NN+n]; }
  for(int i=tid;i<BB*NN;i+=nt) p.out[i]=0.f;
  double a=0.0,q=0.0;
  for(int e=tid;e<NE;e+=nt){
    atomicAdd(&p.counts[p.dst[e]],1);
    int s=p.src[e];
    if(!(s>=FUNC_LO && s<FUNC_HI)){ double v=(double)p.b3[e]; a+=v; q+=v*v; }
  }
  for(int k=tid;k<p.Ksel;k+=nt){
    int s=p.w3r[k*CC]/CC;
    atomicAdd(&p.counts2[s-FUNC_LO],1);
  }
  block_add_slot(a*BB, q*BB, &p.baseS[blockIdx.x&(NSLOT-1)]);
  __shared__ int sFin;
  if(threadIdx.x==0){
    __threadfence();
    int old=atomicAdd(&p.done[LL],1);
    sFin=(old==(int)gridDim.x-1);
  }
  __syncthreads();
  if(!sFin) return;
  scan_one(p.counts, p.row_start, NN);
  __syncthreads();
  scan_one(p.counts2, p.row2, p.F);
}

// Fill: dst-CSR -> slot[e] + packed gather records; non-func-src slots of BOTH
// z3 buffers pre-filled with bf16(b3[e]); src-CSR -> csr2.
__global__ __launch_bounds__(256) void kw_fill(Params p){
  int tid = blockIdx.x*256 + threadIdx.x, nt = gridDim.x*256;
  for(int e=tid;e<NE;e+=nt){
    int n=p.dst[e];
    int pos=p.row_start[n]+atomicAdd(&p.fill[n],1);
    p.slot[e]=pos;
    const float* w=&p.w1v[e*CC];
    int s=p.src[e];
    float b3v=p.b3[e];
    p.grec[pos]=make_uint4(packbf(w[0],w[1]),packbf(w[2],w[3]),
                           packbf(w[4],w[5]),(unsigned int)s);
    if(!(s>=FUNC_LO && s<FUNC_HI)){
      unsigned int hb = f2bf(b3v);
      unsigned int pk = hb | (hb<<16);
      uint4 v4 = make_uint4(pk,pk,pk,pk);
      uint4* za=(uint4*)&p.z3a[pos*BB];
      uint4* zb=(uint4*)&p.z3b[pos*BB];
      za[0]=v4; za[1]=v4; zb[0]=v4; zb[1]=v4;
    }
  }
  for(int k=tid;k<p.Ksel;k+=nt){
    int fi=p.w3r[k*CC]/CC - FUNC_LO;
    int pos=p.row2[fi]+atomicAdd(&p.fill2[fi],1);
    p.csr2[pos]=k;
  }
}

// AB_l (fused, slot-indexed, lazy-BN via running bf16 A; all streams bf16).
// z1_l = b1 + A_l + c1*B + c2*C,   B = sum z3p*w1bf (gathered),
// A_{l+1} = A_l + c1*B + c2*C.  h only maintained for the out-dst tail.
// BN params read from mv[l-1] (8B) — computed by previous layer's last block.
// MODE 0: l==0  gather x0 from xT; store A_init and C; build srec in scatter.
// MODE 1: l==1  (tail h base = xT)   MODE 2: l>=2 (tail h base = h)
template<int MODE>
__global__ __launch_bounds__(256) void kw_AB(Params p, int l,
    const unsigned short* __restrict__ z3p, unsigned short* __restrict__ z3c){
  int tid = blockIdx.x*256 + (int)threadIdx.x, nt = gridDim.x*256;
  float c1=0.f, c2=0.f;
  if(MODE>0){
    float2 mi = p.mv[l-1];
    float g=p.gamma[l-1], be=p.beta[l-1];
    c1 = mi.y*g; c2 = be - mi.x*c1;
  }
  const int FB2 = p.F*32;
  double a=0.0, q=0.0;
  for(int t=tid;t<FB2;t+=nt){
    int fi = t>>5;
    int u  = t&31, b = u&15, half = u>>4;
    int n  = FUNC_LO+fi;
    float acc[CC], cacc[CC];
    #pragma unroll
    for(int i=0;i<CC;i++){ acc[i]=0.f; cacc[i]=0.f; }
    int beg=p.row_start[n], end=p.row_start[n+1];
    int pp = beg + half;
    for(; pp+2<end; pp+=4){
      uint4 g0=p.grec[pp], g1=p.grec[pp+2];
      float2 wa0=ubf2(g0.x), wb0=ubf2(g0.y), wc0=ubf2(g0.z);
      float2 wa1=ubf2(g1.x), wb1=ubf2(g1.y), wc1=ubf2(g1.z);
      float hv0, hv1;
      if(MODE==0){
        int s0=(int)g0.w, s1=(int)g1.w;
        hv0 = p.xT[s0*BB+b];
        hv1 = p.xT[s1*BB+b];
        cacc[0]+=wa0.x+wa1.x; cacc[1]+=wa0.y+wa1.y; cacc[2]+=wb0.x+wb1.x;
        cacc[3]+=wb0.y+wb1.y; cacc[4]+=wc0.x+wc1.x; cacc[5]+=wc0.y+wc1.y;
      } else {
        hv0 = bf2f(z3p[pp*BB+b]);
        hv1 = bf2f(z3p[(pp+2)*BB+b]);
      }
      acc[0]+=hv0*wa0.x+hv1*wa1.x; acc[1]+=hv0*wa0.y+hv1*wa1.y;
      acc[2]+=hv0*wb0.x+hv1*wb1.x; acc[3]+=hv0*wb0.y+hv1*wb1.y;
      acc[4]+=hv0*wc0.x+hv1*wc1.x; acc[5]+=hv0*wc0.y+hv1*wc1.y;
    }
    if(pp<end){
      uint4 g0=p.grec[pp];
      float2 wa0=ubf2(g0.x), wb0=ubf2(g0.y), wc0=ubf2(g0.z);
      float hv0;
      if(MODE==0){
        int s0=(int)g0.w;
        hv0 = p.xT[s0*BB+b];
        cacc[0]+=wa0.x; cacc[1]+=wa0.y; cacc[2]+=wb0.x;
        cacc[3]+=wb0.y; cacc[4]+=wc0.x; cacc[5]+=wc0.y;
      } else {
        hv0 = bf2f(z3p[pp*BB+b]);
      }
      acc[0]+=hv0*wa0.x; acc[1]+=hv0*wa0.y; acc[2]+=hv0*wb0.x;
      acc[3]+=hv0*wb0.y; acc[4]+=hv0*wc0.x; acc[5]+=hv0*wc0.y;
    }
    // combine halves; form z1 via the A recursion
    float z1v[CC];
    #pragma unroll
    for(int i=0;i<CC;i++){
      acc[i] += __shfl_xor(acc[i],16);
      if(MODE==0){
        cacc[i] += __shfl_xor(cacc[i],16);
        if(half==0){
          p.A[(fi*CC+i)*BB+b] = f2bf(acc[i]);
          if(b==0) p.Cw[fi*CC+i] = cacc[i];
        }
        z1v[i] = eluf(acc[i] + p.b1[n*CC+i]);
      } else {
        float Aold = bf2f(p.A[(fi*CC+i)*BB+b]);
        float Cv   = p.Cw[fi*CC+i];
        float Anew = Aold + c1*acc[i] + c2*Cv;
        if(half==0) p.A[(fi*CC+i)*BB+b] = f2bf(Anew);
        z1v[i] = eluf(Anew + p.b1[n*CC+i]);
      }
    }
    const float* W2=&p.w2v[fi*36];
    float z2[CC];
    #pragma unroll
    for(int jj=0;jj<CC;jj++){
      float o=p.b2[n*CC+jj];
      #pragma unroll
      for(int i=0;i<CC;i++) o+=z1v[i]*W2[i*CC+jj];
      z2[jj]=eluf(o);
    }
    int bg2=p.row2[fi], en2=p.row2[fi+1];
    if(MODE==0){
      for(int sp=bg2+half;sp<en2;sp+=2){
        int k=p.csr2[sp];
        int e=p.w3c[k*CC];
        const float* w=&p.w3v[k*CC];
        float b3v=p.b3[e];
        int sl=p.slot[e];
        float2 a01=ubf2(packbf(w[0],w[1]));
        float2 a23=ubf2(packbf(w[2],w[3]));
        float2 a45=ubf2(packbf(w[4],w[5]));
        if(b==0){
          p.srec[sp]=make_uint4(packbf(w[0],w[1]),packbf(w[2],w[3]),
                                packbf(w[4],w[5]),(unsigned int)sl);
          p.sb3[sp]=f2bf(b3v);
        }
        float o = b3v + z2[0]*a01.x+z2[1]*a01.y+z2[2]*a23.x
                      + z2[3]*a23.y+z2[4]*a45.x+z2[5]*a45.y;
        z3c[sl*BB+b]=f2bf(o);
        a+=o; q+=(double)o*o;
      }
    } else {
      for(int sp=bg2+half;sp<en2;sp+=2){
        uint4 s4=p.srec[sp];
        float b3v=bf2f(p.sb3[sp]);
        float2 a01=ubf2(s4.x), a23=ubf2(s4.y), a45=ubf2(s4.z);
        float o = b3v + z2[0]*a01.x + z2[1]*a01.y + z2[2]*a23.x
                      + z2[3]*a23.y + z2[4]*a45.x + z2[5]*a45.y;
        int sl=(int)s4.w;
        z3c[sl*BB+b]=f2bf(o);
        a+=o; q+=(double)o*o;
      }
    }
  }
  // out-dst tail slots: maintain h explicitly (only consumer is kw_out)
  if(MODE>0){
    int outBeg = p.row_start[FUNC_HI];
    int tot = (p.row_start[NN]-outBeg)*BB;
    for(int u=tid; u<tot; u+=nt){
      int pp=outBeg+(u>>4); int bb=u&15;
      float zb=bf2f(z3p[pp*BB+bb]);
      float hb;
      if(MODE==1){
        uint4 g=p.grec[pp];
        int s=(int)g.w;
        hb=p.xT[s*BB+bb];
      } else {
        hb=p.h[pp*BB+bb];
      }
      p.h[pp*BB+bb]=hb+zb*c1+c2;
    }
  }
  block_add_slot(a,q,&p.part[l*NSLOT+(blockIdx.x&(NSLOT-1))]);
  finalize_bn(p,l);
}

// out: only output-node entries (zeroing done in P1). t = j*16 + b.
__global__ __launch_bounds__(256) void kw_out(Params p, const unsigned short* __restrict__ z3p){
  int tid = blockIdx.x*256 + threadIdx.x, nt = gridDim.x*256;
  float2 mi = p.mv[LL-1];
  float g=p.gamma[LL-1], be=p.beta[LL-1];
  float c1=mi.y*g, c2=be-mi.x*c1;
  for(int t=tid;t<NOUT*BB;t+=nt){
    int j=t>>4, b=t&15;
    int n=FUNC_HI+j;
    float acc=0.f;
    int beg=p.row_start[n], end=p.row_start[n+1];
    for(int pp=beg;pp<end;++pp){
      acc += p.h[pp*BB+b] + bf2f(z3p[pp*BB+b])*c1 + c2;
    }
    p.out[b*NN+n]=acc*(1.0f/(float)LL);
  }
}

extern "C" void kernel_launch(void* const* d_in, const int* in_sizes, int n_in,
                              void* d_out, int out_size, void* d_ws, size_t ws_size,
                              hipStream_t stream){
  Params p;
  p.x    =(const float*)d_in[0];
  p.src  =(const int*)  d_in[1];
  p.dst  =(const int*)  d_in[2];
  p.w1v  =(const float*)d_in[6];
  p.b1   =(const float*)d_in[7];
  p.w2v  =(const float*)d_in[10];
  p.b2   =(const float*)d_in[11];
  p.w3r  =(const int*)  d_in[12];
  p.w3c  =(const int*)  d_in[13];
  p.w3v  =(const float*)d_in[14];
  p.b3   =(const float*)d_in[15];
  p.gamma=(const float*)d_in[16];
  p.beta =(const float*)d_in[17];
  p.out  =(float*)d_out;
  p.F    = in_sizes[8]/36;
  p.Ksel = in_sizes[12]/CC;

  char* ws=(char*)d_ws; size_t off=0;
  auto alloc=[&](size_t bytes)->char*{
    char* q=ws+off; off=(off+bytes+255)&~(size_t)255; return q;
  };
  p.row_start=(int*)  alloc((NN+1)*sizeof(int));
  p.row2     =(int*)  alloc((size_t)(p.F+1)*sizeof(int));
  p.slot     =(int*)  alloc(NE*sizeof(int));
  p.csr2     =(int*)  alloc(NE*sizeof(int));
  p.grec     =(uint4*)alloc((size_t)NE*sizeof(uint4));
  p.srec     =(uint4*)alloc((size_t)NE*sizeof(uint4));
  p.sb3      =(unsigned short*)alloc((size_t)NE*sizeof(unsigned short));
  p.xT       =(float*)alloc((size_t)NN*BB*sizeof(float));
  p.h        =(float*)alloc((size_t)NE*BB*sizeof(float));
  p.z3a      =(unsigned short*)alloc((size_t)NE*BB*sizeof(unsigned short));
  p.z3b      =(unsigned short*)alloc((size_t)NE*BB*sizeof(unsigned short));
  p.A        =(unsigned short*)alloc((size_t)p.F*CC*BB*sizeof(unsigned short));
  p.Cw       =(float*)alloc((size_t)p.F*CC*sizeof(float));
  p.mv       =(float2*)alloc(LL*sizeof(float2));
  // zero-initialized block (single memset): counts, fill, counts2, fill2,
  // part, baseS, done
  p.counts   =(int*)  alloc(NN*sizeof(int));
  p.fill     =(int*)  alloc(NN*sizeof(int));
  p.counts2  =(int*)  alloc((size_t)p.F*sizeof(int));
  p.fill2    =(int*)  alloc((size_t)p.F*sizeof(int));
  p.part     =(Slot*) alloc((size_t)LL*NSLOT*sizeof(Slot));
  p.baseS    =(Slot*) alloc((size_t)NSLOT*sizeof(Slot));
  p.done     =(int*)  alloc(8*sizeof(int));
  (void)ws_size; (void)n_in; (void)out_size;

  size_t zspan = (char*)(p.done+8) - (char*)p.counts;
  hipMemsetAsync(p.counts, 0, zspan, stream);

  unsigned short* bufs[2] = { p.z3a, p.z3b };
  const int gridAB = (p.F*32 + 255)/256;

  kw_P1  <<<512,256,0,stream>>>(p);
  kw_fill<<<512,256,0,stream>>>(p);
  kw_AB<0><<<gridAB,256,0,stream>>>(p, 0, bufs[1], bufs[0]);
  kw_AB<1><<<gridAB,256,0,stream>>>(p, 1, bufs[0], bufs[1]);
  for(int l=2;l<LL;l++){
    kw_AB<2><<<gridAB,256,0,stream>>>(p, l, bufs[(l^1)&1], bufs[l&1]);
  }
  kw_out<<<(NOUT*BB+255)/256,256,0,stream>>>(p, bufs[(LL-1)&1]);
}

// Round 17
// 159.636 us; speedup vs baseline: 2.2931x; 2.2931x over previous
//
#include <hip/hip_runtime.h>
#include <math.h>

#define NN 10000
#define NE 100000
#define CC 6
#define LL 6
#define BB 16
#define FUNC_LO 100
#define FUNC_HI 9900
#define NOUT 100
#define EPSF 1e-5f
#define NSLOT 64

struct Slot { double s1, s2; double pad[6]; };  // 64B-padded

struct Params {
  const float *x, *w1v, *b1, *w2v, *b2, *w3v, *b3, *gamma, *beta;
  const int *src, *dst, *w3r, *w3c;
  float *out;
  int *row_start, *counts, *fill, *slot;     // dst-CSR rows; slot[e] = position of e
  int *row2, *counts2, *fill2, *csr2;        // func node -> outgoing selected-edge rows (k)
  uint4 *grec;    // per dst-slot: {bf16 w1[0,1] | w1[2,3] | w1[4,5] | src}
  uint4 *srec;    // per src-slot: {bf16 w3[0,1] | w3[2,3] | w3[4,5] | slot}
  unsigned short *sb3;         // per src-slot: bf16(b3)
  float *xT, *h;
  unsigned short *z3a, *z3b;   // bf16 z3, [slot][16]
  unsigned short *A;           // bf16 [F][CC][BB] running A = sum h*w1
  float *Cw;                   // f32  [F][CC]    constant C = sum w1 (bf16-rounded w1)
  Slot *part, *baseS;
  int F, Ksel;
};

__device__ __forceinline__ float eluf(float x){ return x > 0.0f ? x : expm1f(x); }
__device__ __forceinline__ float bf2f(unsigned short h){
  union { unsigned int u; float f; } c; c.u = ((unsigned int)h)<<16; return c.f;
}
__device__ __forceinline__ unsigned short f2bf(float f){
  union { float f; unsigned int u; } c; c.f = f;
  return (unsigned short)((c.u + 0x7FFFu + ((c.u>>16)&1u)) >> 16);
}
__device__ __forceinline__ unsigned int packbf(float a, float b){
  return (unsigned int)f2bf(a) | ((unsigned int)f2bf(b)<<16);
}
__device__ __forceinline__ float2 ubf2(unsigned int u){
  union { unsigned int u; float f; } lo, hi;
  lo.u = u<<16; hi.u = u & 0xFFFF0000u;
  return make_float2(lo.f, hi.f);
}

__device__ void block_add_slot(double a, double q, Slot* sl){
  __shared__ double sb1[4], sb2[4];
  #pragma unroll
  for(int off=32;off;off>>=1){ a+=__shfl_down(a,off); q+=__shfl_down(q,off); }
  int wid = threadIdx.x>>6;
  if((threadIdx.x&63)==0){ sb1[wid]=a; sb2[wid]=q; }
  __syncthreads();
  if(threadIdx.x==0){
    double A=sb1[0]+sb1[1]+sb1[2]+sb1[3];
    double Q=sb2[0]+sb2[1]+sb2[2]+sb2[3];
    if(A!=0.0) atomicAdd(&sl->s1,A);
    if(Q!=0.0) atomicAdd(&sl->s2,Q);
  }
  __syncthreads();
}

__device__ void bn_params(const Slot* part, const Slot* baseS, float* m, float* inv){
  __shared__ double s_mv[2];
  if(threadIdx.x < NSLOT){
    double a = part[threadIdx.x].s1 + baseS[threadIdx.x].s1;
    double q = part[threadIdx.x].s2 + baseS[threadIdx.x].s2;
    #pragma unroll
    for(int off=32;off;off>>=1){ a+=__shfl_down(a,off); q+=__shfl_down(q,off); }
    if(threadIdx.x==0){
      const double cnt = (double)NE*(double)BB;
      double md = a/cnt, vd = q/cnt - md*md;
      s_mv[0]=md; s_mv[1]=1.0/sqrt(vd+(double)EPSF);
    }
  }
  __syncthreads();
  *m=(float)s_mv[0]; *inv=(float)s_mv[1];
  __syncthreads();
}

// P1: transpose x -> xT; dst histogram; src-selected histogram; base BN sums;
// zero the output buffer.
__global__ __launch_bounds__(256) void kw_P1(Params p){
  int tid = blockIdx.x*256 + threadIdx.x, nt = gridDim.x*256;
  for(int i=tid;i<NN*BB;i+=nt){ int n=i>>4, b=i&15; p.xT[i]=p.x[b*NN+n]; }
  for(int i=tid;i<BB*NN;i+=nt) p.out[i]=0.f;
  double a=0.0,q=0.0;
  for(int e=tid;e<NE;e+=nt){
    atomicAdd(&p.counts[p.dst[e]],1);
    int s=p.src[e];
    if(!(s>=FUNC_LO && s<FUNC_HI)){ double v=(double)p.b3[e]; a+=v; q+=v*v; }
  }
  for(int k=tid;k<p.Ksel;k+=nt){
    int s=p.w3r[k*CC]/CC;
    atomicAdd(&p.counts2[s-FUNC_LO],1);
  }
  block_add_slot(a*BB, q*BB, &p.baseS[blockIdx.x&(NSLOT-1)]);
}

// Two independent single-block scans: block 0 -> dst-CSR, block 1 -> src-CSR.
__global__ __launch_bounds__(256) void kw_scan(Params p){
  __shared__ int s_scan[256];
  const int*  cin  = (blockIdx.x==0)? p.counts : p.counts2;
  int*        rout = (blockIdx.x==0)? p.row_start : p.row2;
  const int   nel  = (blockIdx.x==0)? NN : p.F;
  const int   CH   = (nel+255)/256;
  int t=threadIdx.x, base=t*CH, s=0;
  for(int k=0;k<CH;k++){ int i=base+k; if(i<nel) s+=cin[i]; }
  s_scan[t]=s; __syncthreads();
  for(int off=1;off<256;off<<=1){
    int v=(t>=off)?s_scan[t-off]:0; __syncthreads();
    s_scan[t]+=v; __syncthreads();
  }
  int run=s_scan[t]-s;
  for(int k=0;k<CH;k++){ int i=base+k; if(i<nel){ rout[i]=run; run+=cin[i]; } }
  if(t==255) rout[nel]=s_scan[255];
}

// Fill: dst-CSR -> slot[e] + packed gather records; non-func-src slots of BOTH
// z3 buffers pre-filled with bf16(b3[e]); src-CSR -> csr2.
__global__ __launch_bounds__(256) void kw_fill(Params p){
  int tid = blockIdx.x*256 + threadIdx.x, nt = gridDim.x*256;
  for(int e=tid;e<NE;e+=nt){
    int n=p.dst[e];
    int pos=p.row_start[n]+atomicAdd(&p.fill[n],1);
    p.slot[e]=pos;
    const float* w=&p.w1v[e*CC];
    int s=p.src[e];
    float b3v=p.b3[e];
    p.grec[pos]=make_uint4(packbf(w[0],w[1]),packbf(w[2],w[3]),
                           packbf(w[4],w[5]),(unsigned int)s);
    if(!(s>=FUNC_LO && s<FUNC_HI)){
      unsigned int hb = f2bf(b3v);
      unsigned int pk = hb | (hb<<16);
      uint4 v4 = make_uint4(pk,pk,pk,pk);
      uint4* za=(uint4*)&p.z3a[pos*BB];
      uint4* zb=(uint4*)&p.z3b[pos*BB];
      za[0]=v4; za[1]=v4; zb[0]=v4; zb[1]=v4;
    }
  }
  for(int k=tid;k<p.Ksel;k+=nt){
    int fi=p.w3r[k*CC]/CC - FUNC_LO;
    int pos=p.row2[fi]+atomicAdd(&p.fill2[fi],1);
    p.csr2[pos]=k;
  }
}

// AB_l (fused, slot-indexed, lazy-BN via running bf16 A; all streams bf16).
// z1_l = b1 + A_l + c1*B + c2*C,   B = sum z3p*w1bf (gathered),
// A_{l+1} = A_l + c1*B + c2*C.  h only maintained for the out-dst tail.
// MODE 0: l==0  gather x0 from xT; store A_init and C; build srec in scatter.
// MODE 1: l==1  (tail h base = xT)   MODE 2: l>=2 (tail h base = h)
template<int MODE>
__global__ __launch_bounds__(256) void kw_AB(Params p, int l,
    const unsigned short* __restrict__ z3p, unsigned short* __restrict__ z3c){
  int tid = blockIdx.x*256 + (int)threadIdx.x, nt = gridDim.x*256;
  float c1=0.f, c2=0.f;
  if(MODE>0){
    float m, inv;
    bn_params(p.part+(l-1)*NSLOT, p.baseS, &m, &inv);
    float g=p.gamma[l-1], be=p.beta[l-1];
    c1 = inv*g; c2 = be - m*c1;
  }
  const int FB2 = p.F*32;
  double a=0.0, q=0.0;
  for(int t=tid;t<FB2;t+=nt){
    int fi = t>>5;
    int u  = t&31, b = u&15, half = u>>4;
    int n  = FUNC_LO+fi;
    float acc[CC], cacc[CC];
    #pragma unroll
    for(int i=0;i<CC;i++){ acc[i]=0.f; cacc[i]=0.f; }
    int beg=p.row_start[n], end=p.row_start[n+1];
    int pp = beg + half;
    for(; pp+2<end; pp+=4){
      uint4 g0=p.grec[pp], g1=p.grec[pp+2];
      float2 wa0=ubf2(g0.x), wb0=ubf2(g0.y), wc0=ubf2(g0.z);
      float2 wa1=ubf2(g1.x), wb1=ubf2(g1.y), wc1=ubf2(g1.z);
      float hv0, hv1;
      if(MODE==0){
        int s0=(int)g0.w, s1=(int)g1.w;
        hv0 = p.xT[s0*BB+b];
        hv1 = p.xT[s1*BB+b];
        cacc[0]+=wa0.x+wa1.x; cacc[1]+=wa0.y+wa1.y; cacc[2]+=wb0.x+wb1.x;
        cacc[3]+=wb0.y+wb1.y; cacc[4]+=wc0.x+wc1.x; cacc[5]+=wc0.y+wc1.y;
      } else {
        hv0 = bf2f(z3p[pp*BB+b]);
        hv1 = bf2f(z3p[(pp+2)*BB+b]);
      }
      acc[0]+=hv0*wa0.x+hv1*wa1.x; acc[1]+=hv0*wa0.y+hv1*wa1.y;
      acc[2]+=hv0*wb0.x+hv1*wb1.x; acc[3]+=hv0*wb0.y+hv1*wb1.y;
      acc[4]+=hv0*wc0.x+hv1*wc1.x; acc[5]+=hv0*wc0.y+hv1*wc1.y;
    }
    if(pp<end){
      uint4 g0=p.grec[pp];
      float2 wa0=ubf2(g0.x), wb0=ubf2(g0.y), wc0=ubf2(g0.z);
      float hv0;
      if(MODE==0){
        int s0=(int)g0.w;
        hv0 = p.xT[s0*BB+b];
        cacc[0]+=wa0.x; cacc[1]+=wa0.y; cacc[2]+=wb0.x;
        cacc[3]+=wb0.y; cacc[4]+=wc0.x; cacc[5]+=wc0.y;
      } else {
        hv0 = bf2f(z3p[pp*BB+b]);
      }
      acc[0]+=hv0*wa0.x; acc[1]+=hv0*wa0.y; acc[2]+=hv0*wb0.x;
      acc[3]+=hv0*wb0.y; acc[4]+=hv0*wc0.x; acc[5]+=hv0*wc0.y;
    }
    // combine halves; form z1 via the A recursion
    float z1v[CC];
    #pragma unroll
    for(int i=0;i<CC;i++){
      acc[i] += __shfl_xor(acc[i],16);
      if(MODE==0){
        cacc[i] += __shfl_xor(cacc[i],16);
        if(half==0){
          p.A[(fi*CC+i)*BB+b] = f2bf(acc[i]);
          if(b==0) p.Cw[fi*CC+i] = cacc[i];
        }
        z1v[i] = eluf(acc[i] + p.b1[n*CC+i]);
      } else {
        float Aold = bf2f(p.A[(fi*CC+i)*BB+b]);
        float Cv   = p.Cw[fi*CC+i];
        float Anew = Aold + c1*acc[i] + c2*Cv;
        if(half==0) p.A[(fi*CC+i)*BB+b] = f2bf(Anew);
        z1v[i] = eluf(Anew + p.b1[n*CC+i]);
      }
    }
    const float* W2=&p.w2v[fi*36];
    float z2[CC];
    #pragma unroll
    for(int jj=0;jj<CC;jj++){
      float o=p.b2[n*CC+jj];
      #pragma unroll
      for(int i=0;i<CC;i++) o+=z1v[i]*W2[i*CC+jj];
      z2[jj]=eluf(o);
    }
    int bg2=p.row2[fi], en2=p.row2[fi+1];
    if(MODE==0){
      for(int sp=bg2+half;sp<en2;sp+=2){
        int k=p.csr2[sp];
        int e=p.w3c[k*CC];
        const float* w=&p.w3v[k*CC];
        float b3v=p.b3[e];
        int sl=p.slot[e];
        // bf16-rounded w3 used consistently for compute and storage
        float2 a01=ubf2(packbf(w[0],w[1]));
        float2 a23=ubf2(packbf(w[2],w[3]));
        float2 a45=ubf2(packbf(w[4],w[5]));
        if(b==0){
          p.srec[sp]=make_uint4(packbf(w[0],w[1]),packbf(w[2],w[3]),
                                packbf(w[4],w[5]),(unsigned int)sl);
          p.sb3[sp]=f2bf(b3v);
        }
        float o = b3v + z2[0]*a01.x+z2[1]*a01.y+z2[2]*a23.x
                      + z2[3]*a23.y+z2[4]*a45.x+z2[5]*a45.y;
        z3c[sl*BB+b]=f2bf(o);
        a+=o; q+=(double)o*o;
      }
    } else {
      for(int sp=bg2+half;sp<en2;sp+=2){
        uint4 s4=p.srec[sp];
        float b3v=bf2f(p.sb3[sp]);
        float2 a01=ubf2(s4.x), a23=ubf2(s4.y), a45=ubf2(s4.z);
        float o = b3v + z2[0]*a01.x + z2[1]*a01.y + z2[2]*a23.x
                      + z2[3]*a23.y + z2[4]*a45.x + z2[5]*a45.y;
        int sl=(int)s4.w;
        z3c[sl*BB+b]=f2bf(o);
        a+=o; q+=(double)o*o;
      }
    }
  }
  // out-dst tail slots: maintain h explicitly (only consumer is kw_out)
  if(MODE>0){
    int outBeg = p.row_start[FUNC_HI];
    int tot = (p.row_start[NN]-outBeg)*BB;
    for(int u=tid; u<tot; u+=nt){
      int pp=outBeg+(u>>4); int bb=u&15;
      float zb=bf2f(z3p[pp*BB+bb]);
      float hb;
      if(MODE==1){
        uint4 g=p.grec[pp];
        int s=(int)g.w;
        hb=p.xT[s*BB+bb];
      } else {
        hb=p.h[pp*BB+bb];
      }
      p.h[pp*BB+bb]=hb+zb*c1+c2;
    }
  }
  block_add_slot(a,q,&p.part[l*NSLOT+(blockIdx.x&(NSLOT-1))]);
}

// out: only output-node entries (zeroing done in P1). t = j*16 + b.
__global__ __launch_bounds__(256) void kw_out(Params p, const unsigned short* __restrict__ z3p){
  int tid = blockIdx.x*256 + threadIdx.x, nt = gridDim.x*256;
  float m,inv;
  bn_params(p.part+(LL-1)*NSLOT, p.baseS, &m, &inv);
  float g=p.gamma[LL-1], be=p.beta[LL-1];
  float c1=inv*g, c2=be-m*c1;
  for(int t=tid;t<NOUT*BB;t+=nt){
    int j=t>>4, b=t&15;
    int n=FUNC_HI+j;
    float acc=0.f;
    int beg=p.row_start[n], end=p.row_start[n+1];
    for(int pp=beg;pp<end;++pp){
      acc += p.h[pp*BB+b] + bf2f(z3p[pp*BB+b])*c1 + c2;
    }
    p.out[b*NN+n]=acc*(1.0f/(float)LL);
  }
}

extern "C" void kernel_launch(void* const* d_in, const int* in_sizes, int n_in,
                              void* d_out, int out_size, void* d_ws, size_t ws_size,
                              hipStream_t stream){
  Params p;
  p.x    =(const float*)d_in[0];
  p.src  =(const int*)  d_in[1];
  p.dst  =(const int*)  d_in[2];
  p.w1v  =(const float*)d_in[6];
  p.b1   =(const float*)d_in[7];
  p.w2v  =(const float*)d_in[10];
  p.b2   =(const float*)d_in[11];
  p.w3r  =(const int*)  d_in[12];
  p.w3c  =(const int*)  d_in[13];
  p.w3v  =(const float*)d_in[14];
  p.b3   =(const float*)d_in[15];
  p.gamma=(const float*)d_in[16];
  p.beta =(const float*)d_in[17];
  p.out  =(float*)d_out;
  p.F    = in_sizes[8]/36;
  p.Ksel = in_sizes[12]/CC;

  char* ws=(char*)d_ws; size_t off=0;
  auto alloc=[&](size_t bytes)->char*{
    char* q=ws+off; off=(off+bytes+255)&~(size_t)255; return q;
  };
  p.row_start=(int*)  alloc((NN+1)*sizeof(int));
  p.row2     =(int*)  alloc((size_t)(p.F+1)*sizeof(int));
  p.slot     =(int*)  alloc(NE*sizeof(int));
  p.csr2     =(int*)  alloc(NE*sizeof(int));
  p.grec     =(uint4*)alloc((size_t)NE*sizeof(uint4));
  p.srec     =(uint4*)alloc((size_t)NE*sizeof(uint4));
  p.sb3      =(unsigned short*)alloc((size_t)NE*sizeof(unsigned short));
  p.xT       =(float*)alloc((size_t)NN*BB*sizeof(float));
  p.h        =(float*)alloc((size_t)NE*BB*sizeof(float));
  p.z3a      =(unsigned short*)alloc((size_t)NE*BB*sizeof(unsigned short));
  p.z3b      =(unsigned short*)alloc((size_t)NE*BB*sizeof(unsigned short));
  p.A        =(unsigned short*)alloc((size_t)p.F*CC*BB*sizeof(unsigned short));
  p.Cw       =(float*)alloc((size_t)p.F*CC*sizeof(float));
  // zero-initialized block (single memset): counts, fill, counts2, fill2, part, baseS
  p.counts   =(int*)  alloc(NN*sizeof(int));
  p.fill     =(int*)  alloc(NN*sizeof(int));
  p.counts2  =(int*)  alloc((size_t)p.F*sizeof(int));
  p.fill2    =(int*)  alloc((size_t)p.F*sizeof(int));
  p.part     =(Slot*) alloc((size_t)LL*NSLOT*sizeof(Slot));
  p.baseS    =(Slot*) alloc((size_t)NSLOT*sizeof(Slot));
  (void)ws_size; (void)n_in; (void)out_size;

  size_t zspan = (char*)(p.baseS+NSLOT) - (char*)p.counts;
  hipMemsetAsync(p.counts, 0, zspan, stream);

  unsigned short* bufs[2] = { p.z3a, p.z3b };
  const int gridAB = (p.F*32 + 255)/256;

  kw_P1  <<<512,256,0,stream>>>(p);
  kw_scan<<<2,  256,0,stream>>>(p);
  kw_fill<<<512,256,0,stream>>>(p);
  kw_AB<0><<<gridAB,256,0,stream>>>(p, 0, bufs[1], bufs[0]);
  kw_AB<1><<<gridAB,256,0,stream>>>(p, 1, bufs[0], bufs[1]);
  for(int l=2;l<LL;l++){
    kw_AB<2><<<gridAB,256,0,stream>>>(p, l, bufs[(l^1)&1], bufs[l&1]);
  }
  kw_out<<<(NOUT*BB+255)/256,256,0,stream>>>(p, bufs[(LL-1)&1]);
}